// Round 1
// baseline (418.110 us; speedup 1.0000x reference)
//
#include <hip/hip_runtime.h>
#include <hip/hip_bf16.h>
#include <stdint.h>

// Problem constants
#define S_LEN 1024
#define B_SZ  64
#define I_SZ  512
#define H_SZ  2048
#define O_SZ  512

typedef __bf16  bf16x8 __attribute__((ext_vector_type(8)));
typedef float   f32x4  __attribute__((ext_vector_type(4)));

static __device__ __forceinline__ ushort f2bf(float f) {
  union { float f; unsigned u; } v; v.f = f;
  unsigned r = v.u + 0x7FFFu + ((v.u >> 16) & 1u);   // RNE
  return (ushort)(r >> 16);
}
static __device__ __forceinline__ float bf2f(ushort u) {
  return __builtin_bit_cast(float, (unsigned)u << 16);
}

// async global->LDS, 16B per lane, wave-uniform LDS base + lane*16
#define GLOAD_LDS16(gp, lp) \
  __builtin_amdgcn_global_load_lds( \
      (__attribute__((address_space(1))) void*)(gp), \
      (__attribute__((address_space(3))) void*)(lp), 16, 0, 0)

// ---------------------------------------------------------------- W convert (tiny)
__global__ __launch_bounds__(256) void convert_f32_bf16_kernel(
    const float4* __restrict__ in, ushort4* __restrict__ out, int n4) {
  int i = blockIdx.x * 256 + threadIdx.x;
  if (i >= n4) return;
  float4 v = in[i];
  ushort4 o; o.x = f2bf(v.x); o.y = f2bf(v.y); o.z = f2bf(v.z); o.w = f2bf(v.w);
  out[i] = o;
}

// ---------------------------------------------------------------- Y = bias (runs BEFORE fused)
__global__ __launch_bounds__(256) void init_y_kernel(
    const float* __restrict__ bho, float* __restrict__ Y) {
  int idx = blockIdx.x * 256 + threadIdx.x;   // 0..32767
  Y[idx] = bho[idx & (O_SZ - 1)];
}

// convert prefetched fp32 regs -> bf16 -> ds_write into As (stride 72, 2-way banks)
#define CVT_WRITE_A() do { \
    _Pragma("unroll") \
    for (int j_ = 0; j_ < 4; ++j_) { \
      union { __bf16 h[8]; uint4 v; } uvt_; \
      uvt_.h[0] = (__bf16)ar[2*j_].x;   uvt_.h[1] = (__bf16)ar[2*j_].y; \
      uvt_.h[2] = (__bf16)ar[2*j_].z;   uvt_.h[3] = (__bf16)ar[2*j_].w; \
      uvt_.h[4] = (__bf16)ar[2*j_+1].x; uvt_.h[5] = (__bf16)ar[2*j_+1].y; \
      uvt_.h[6] = (__bf16)ar[2*j_+1].z; uvt_.h[7] = (__bf16)ar[2*j_+1].w; \
      *(uint4*)&As[(arow0 + j_ * 8) * 72 + (lane & 7) * 8] = uvt_.v; \
    } } while (0)

// register prefetch of X tile T (8 float4 = one 8-row x 64-col slice per thread)
#define PREFETCH_A(T) do { \
    const float* gp_ = X + offA + (size_t)((T) >> 3) * (128 * B_SZ * I_SZ) \
                         + (size_t)(((T) & 7) * 64); \
    _Pragma("unroll") \
    for (int j_ = 0; j_ < 4; ++j_) { \
      ar[2*j_]   = *(const float4*)(gp_ + (size_t)j_ * (8 * B_SZ * I_SZ)); \
      ar[2*j_+1] = *(const float4*)(gp_ + (size_t)j_ * (8 * B_SZ * I_SZ) + 4); \
    } } while (0)

#define SCAN16(colp, s0_) do { \
    ushort4 v0 = *(const ushort4*)&(colp)[(s0_)]; \
    ushort4 v1 = *(const ushort4*)&(colp)[(s0_) + 4]; \
    ushort4 v2 = *(const ushort4*)&(colp)[(s0_) + 8]; \
    ushort4 v3 = *(const ushort4*)&(colp)[(s0_) + 12]; \
    p = fmaf(c, fabsf(p), bf2f(v0.x)); p = fmaf(c, fabsf(p), bf2f(v0.y)); \
    p = fmaf(c, fabsf(p), bf2f(v0.z)); p = fmaf(c, fabsf(p), bf2f(v0.w)); \
    p = fmaf(c, fabsf(p), bf2f(v1.x)); p = fmaf(c, fabsf(p), bf2f(v1.y)); \
    p = fmaf(c, fabsf(p), bf2f(v1.z)); p = fmaf(c, fabsf(p), bf2f(v1.w)); \
    p = fmaf(c, fabsf(p), bf2f(v2.x)); p = fmaf(c, fabsf(p), bf2f(v2.y)); \
    p = fmaf(c, fabsf(p), bf2f(v2.z)); p = fmaf(c, fabsf(p), bf2f(v2.w)); \
    p = fmaf(c, fabsf(p), bf2f(v3.x)); p = fmaf(c, fabsf(p), bf2f(v3.y)); \
    p = fmaf(c, fabsf(p), bf2f(v3.z)); p = fmaf(c, fabsf(p), bf2f(v3.w)); \
  } while (0)

// ---------------------------------------------------------------- fused GEMM + scan + projection
// Grid: 1024 blocks = (b, ht). Block computes u[s, b, ht*128..+128) as 64 linear
// K-steps (8 s-tiles x 8 kt), single-buffered LDS with a frags-to-regs-early
// pipeline: per kt {16 ds_read -> lgkmcnt(0) -> s_barrier -> restage(t+1) ->
// MFMA -> vmcnt(8) -> s_barrier}. The 8 A-prefetch HBM loads (tile t+2) stay
// in flight ACROSS both barriers (never drained to 0 in the loop). Cs is a
// separate buffer; the 128-step serial scan of s-tile st-1 is chopped into 8
// 16-step chunks hidden inside the staging shadow of s-tile st. Tail: h is
// projected through Who and atomically accumulated into Y (bias pre-seeded).
__global__ __launch_bounds__(256, 2) void fused_gemm_scan_kernel(
    const float* __restrict__ X,      // [1024][64][512] fp32
    const ushort* __restrict__ Wbf,   // [2048][512] bf16
    const float* __restrict__ hh,     // [2048]
    const float* __restrict__ Who,    // [512][2048] fp32
    float* __restrict__ Y) {          // [64][512], pre-seeded with bias
  __shared__ __align__(16) ushort smem[34304];   // 68608 B -> 2 blocks/CU
  ushort* As = smem;                  // [128][72]
  ushort* Bs = smem + 9216;           // [128][64], rotate-swizzled
  ushort* Cs = smem + 17408;          // [128 h][132 s]  (separate: no overlay)

  const int tid  = threadIdx.x;
  const int wave = tid >> 6;
  const int lane = tid & 63;

  const int bid = blockIdx.x;
  const int xcd = bid & 7;            // XCD (bid%8 heuristic)
  const int g   = bid >> 3;           // 0..127
  const int b   = (xcd << 3) | (g & 7);  // same-b -> same XCD (X L2 reuse)
  const int ht  = g >> 3;             // h-tile 0..15

  const int wm = (wave >> 1) * 64;    // s-offset within tile
  const int wn = (wave & 1) * 64;     // h-offset within tile
  const int ml = lane & 15;
  const int q  = lane >> 4;

  // A staging assignment (register prefetch path, fp32 X read directly)
  const int arow0 = wave * 32 + (lane >> 3);
  const size_t offA = (size_t)arow0 * (B_SZ * I_SZ) + (size_t)b * I_SZ
                    + (size_t)((lane & 7) * 8);

  // B staging: wave stages 32 rows; slot s holds chunk (s - row)&7
  const int r0     = wave * 32;
  const int srow   = lane >> 3;
  const int schunk = ((lane & 7) - srow) & 7;
  const ushort* gB = Wbf + (size_t)(ht * 128 + r0 + srow) * I_SZ + schunk * 8;
  ushort* lB = Bs + r0 * 64;

  // fragment offsets
  const int aoff0 = q * 8;                    // A: slot == chunk, stride 72
  const int aoff1 = (4 + q) * 8;
  const int boff0 = ((q + ml) & 7) * 8;       // B: rotate swizzle, stride 64
  const int boff1 = ((4 + q + ml) & 7) * 8;
  int arow[4], brow[4];
  #pragma unroll
  for (int i = 0; i < 4; ++i) {
    arow[i] = (wm + i * 16 + ml) * 72;
    brow[i] = (wn + i * 16 + ml) * 64;
  }

  float c = 0.0f, p = 0.0f;           // scan state (p: pre-abs h)
  if (tid < 128) c = hh[ht * 128 + tid];

  float4 ar[8];

  // ---------------- prologue: stage tile 0 fully, prefetch ar <- tile 1
  #pragma unroll
  for (int jj = 0; jj < 4; ++jj)
    GLOAD_LDS16(gB + (size_t)(jj * 8) * I_SZ, lB + jj * 512);   // B tile0 (kt=0)
  __builtin_amdgcn_sched_barrier(0);   // B loads are oldest in vmem queue
  PREFETCH_A(0);                       // (compiler waits these before cvt)
  CVT_WRITE_A();                       // A tile0 -> LDS
  PREFETCH_A(1);                       // ar <- tile 1, stays in flight
  __builtin_amdgcn_sched_barrier(0);
  asm volatile("s_waitcnt vmcnt(8) lgkmcnt(0)" ::: "memory");
  __builtin_amdgcn_sched_barrier(0);
  __builtin_amdgcn_s_barrier();        // tile 0 visible

  f32x4 acc[4][4];

  #pragma unroll 1
  for (int t = 0; t < 64; ++t) {       // t = st*8 + kt
    const int kt = t & 7;
    if (kt == 0) {
      #pragma unroll
      for (int mi = 0; mi < 4; ++mi)
        #pragma unroll
        for (int ni = 0; ni < 4; ++ni) {
          f32x4 z = {0.f, 0.f, 0.f, 0.f};
          acc[mi][ni] = z;
        }
    }

    // ---- fragment reads of tile t -> registers (frees LDS at the barrier)
    bf16x8 a0[4], a1[4], b0[4], b1[4];
    #pragma unroll
    for (int i = 0; i < 4; ++i) {
      a0[i] = *(const bf16x8*)&As[arow[i] + aoff0];
      a1[i] = *(const bf16x8*)&As[arow[i] + aoff1];
      b0[i] = *(const bf16x8*)&Bs[brow[i] + boff0];
      b1[i] = *(const bf16x8*)&Bs[brow[i] + boff1];
    }
    __builtin_amdgcn_sched_barrier(0);
    asm volatile("s_waitcnt lgkmcnt(0)" ::: "memory");
    __builtin_amdgcn_sched_barrier(0);
    __builtin_amdgcn_s_barrier();      // B_a: all waves done reading -> LDS free

    // ---- restage tile t+1 (loads fly under this kt's MFMA)
    if (t < 63) {
      const int k1 = (t + 1) & 7;
      #pragma unroll
      for (int jj = 0; jj < 4; ++jj)
        GLOAD_LDS16(gB + (size_t)(jj * 8) * I_SZ + k1 * 64, lB + jj * 512);
    }
    __builtin_amdgcn_sched_barrier(0); // pin: B gloads issued before anything below
    if (t < 63) {
      CVT_WRITE_A();                   // A tile t+1 (ar loaded during t-1)
      if (t < 62) PREFETCH_A(t + 2);   // ar <- tile t+2 (HBM latency spans the kt)
    }

    // ---- scan chunk of s-tile (t>>3)-1 (hidden in the staging shadow)
    if (t >= 8 && tid < 128) {
      const ushort* col = &Cs[tid * 132];
      const int s0 = kt * 16;
      SCAN16(col, s0);
    }

    // ---- MFMA (from registers)
    __builtin_amdgcn_s_setprio(1);
    #pragma unroll
    for (int mi = 0; mi < 4; ++mi)
      #pragma unroll
      for (int ni = 0; ni < 4; ++ni)
        acc[mi][ni] = __builtin_amdgcn_mfma_f32_16x16x32_bf16(
            a0[mi], b0[ni], acc[mi][ni], 0, 0, 0);
    #pragma unroll
    for (int mi = 0; mi < 4; ++mi)
      #pragma unroll
      for (int ni = 0; ni < 4; ++ni)
        acc[mi][ni] = __builtin_amdgcn_mfma_f32_16x16x32_bf16(
            a1[mi], b1[ni], acc[mi][ni], 0, 0, 0);
    __builtin_amdgcn_s_setprio(0);

    // ---- counted wait: retire the 4 B gloads, keep the 8 A-prefetch in flight
    __builtin_amdgcn_sched_barrier(0);
    if (t < 62) {
      asm volatile("s_waitcnt vmcnt(8) lgkmcnt(0)" ::: "memory");
    } else {
      asm volatile("s_waitcnt vmcnt(0) lgkmcnt(0)" ::: "memory");  // no prefetch issued
    }
    __builtin_amdgcn_sched_barrier(0);
    __builtin_amdgcn_s_barrier();      // B_b: tile t+1 visible

    // ---- end of s-tile: acc -> transposed Cs[h][s] (conflict-free ds_write_b64)
    if (kt == 7) {
      const int sb = wm + q * 4;
      #pragma unroll
      for (int mi = 0; mi < 4; ++mi)
        #pragma unroll
        for (int ni = 0; ni < 4; ++ni) {
          ushort4 o;
          o.x = f2bf(acc[mi][ni][0]); o.y = f2bf(acc[mi][ni][1]);
          o.z = f2bf(acc[mi][ni][2]); o.w = f2bf(acc[mi][ni][3]);
          *(ushort4*)&Cs[(wn + ni * 16 + ml) * 132 + sb + mi * 16] = o;
        }
    }
  }

  __syncthreads();                     // st=7 Cs visible (full drain OK, once)

  // ---- final s-tile scan + h handoff
  if (tid < 128) {
    const ushort* col = &Cs[tid * 132];
    #pragma unroll
    for (int s0 = 0; s0 < 128; s0 += 16) {
      SCAN16(col, s0);
    }
    ((float*)smem)[tid] = fabsf(p);    // h_s overlays As (free now)
  }
  __syncthreads();

  // ---- Y[b, :] += h . Who[:, ht*128 .. +128)   (Who slice is L2-resident)
  {
    const float* hs = (const float*)smem;
    const float* w0 = Who + (size_t)tid * H_SZ + (size_t)ht * 128;
    const float* w1 = w0 + (size_t)256 * H_SZ;
    float y0 = 0.f, y1 = 0.f;
    #pragma unroll 8
    for (int k = 0; k < 128; k += 4) {
      float4 hv = *(const float4*)&hs[k];    // broadcast (same addr all lanes)
      float4 u0 = *(const float4*)&w0[k];
      float4 u1 = *(const float4*)&w1[k];
      y0 += hv.x * u0.x + hv.y * u0.y + hv.z * u0.z + hv.w * u0.w;
      y1 += hv.x * u1.x + hv.y * u1.y + hv.z * u1.z + hv.w * u1.w;
    }
    atomicAdd(&Y[(size_t)b * O_SZ + tid], y0);
    atomicAdd(&Y[(size_t)b * O_SZ + 256 + tid], y1);
  }
}

// ---------------------------------------------------------------- launch
extern "C" void kernel_launch(void* const* d_in, const int* in_sizes, int n_in,
                              void* d_out, int out_size, void* d_ws, size_t ws_size,
                              hipStream_t stream) {
  (void)in_sizes; (void)n_in; (void)out_size; (void)ws_size;
  const float* X   = (const float*)d_in[0];   // [1024][64][512]
  const float* Wih = (const float*)d_in[1];   // [2048][512]
  const float* hh  = (const float*)d_in[2];   // [2048]
  const float* Who = (const float*)d_in[3];   // [512][2048]
  const float* bho = (const float*)d_in[4];   // [512]
  float* Y = (float*)d_out;                   // [64][512]

  ushort* Wbf = (ushort*)d_ws;                // 2 MiB

  // W convert (tiny)
  {
    int n4w = (int)((size_t)H_SZ * I_SZ / 4);          // 262144
    convert_f32_bf16_kernel<<<n4w / 256, 256, 0, stream>>>(
        (const float4*)Wih, (ushort4*)Wbf, n4w);
  }

  // Y <- bias (must complete before fused kernel's atomics; stream-ordered)
  init_y_kernel<<<(B_SZ * O_SZ) / 256, 256, 0, stream>>>(bho, Y);

  // fused GEMM + scan + projection
  fused_gemm_scan_kernel<<<1024, 256, 0, stream>>>(X, Wbf, hh, Who, Y);
}

// Round 2
// 406.598 us; speedup vs baseline: 1.0283x; 1.0283x over previous
//
#include <hip/hip_runtime.h>
#include <hip/hip_bf16.h>
#include <stdint.h>

// Problem constants
#define S_LEN 1024
#define B_SZ  64
#define I_SZ  512
#define H_SZ  2048
#define O_SZ  512

typedef __bf16  bf16x8 __attribute__((ext_vector_type(8)));
typedef float   f32x4  __attribute__((ext_vector_type(4)));

static __device__ __forceinline__ ushort f2bf(float f) {
  union { float f; unsigned u; } v; v.f = f;
  unsigned r = v.u + 0x7FFFu + ((v.u >> 16) & 1u);   // RNE
  return (ushort)(r >> 16);
}
static __device__ __forceinline__ float bf2f(ushort u) {
  return __builtin_bit_cast(float, (unsigned)u << 16);
}

// async global->LDS, 16B per lane, wave-uniform LDS base + lane*16
#define GLOAD_LDS16(gp, lp) \
  __builtin_amdgcn_global_load_lds( \
      (__attribute__((address_space(1))) void*)(gp), \
      (__attribute__((address_space(3))) void*)(lp), 16, 0, 0)

// ---------------------------------------------------------------- W convert (tiny)
__global__ __launch_bounds__(256) void convert_f32_bf16_kernel(
    const float4* __restrict__ in, ushort4* __restrict__ out, int n4) {
  int i = blockIdx.x * 256 + threadIdx.x;
  if (i >= n4) return;
  float4 v = in[i];
  ushort4 o; o.x = f2bf(v.x); o.y = f2bf(v.y); o.z = f2bf(v.z); o.w = f2bf(v.w);
  out[i] = o;
}

// ---------------------------------------------------------------- Y = bias (runs BEFORE fused)
__global__ __launch_bounds__(256) void init_y_kernel(
    const float* __restrict__ bho, float* __restrict__ Y) {
  int idx = blockIdx.x * 256 + threadIdx.x;   // 0..32767
  Y[idx] = bho[idx & (O_SZ - 1)];
}

// register prefetch of X tile T (8 float4 = one 8-row x 64-col slice per thread)
#define PREF(AR, T) do { \
    const float* gp_ = X + offA + (size_t)((T) >> 3) * (128 * B_SZ * I_SZ) \
                         + (size_t)(((T) & 7) * 64); \
    _Pragma("unroll") \
    for (int j_ = 0; j_ < 4; ++j_) { \
      AR[2*j_]   = *(const float4*)(gp_ + (size_t)j_ * (8 * B_SZ * I_SZ)); \
      AR[2*j_+1] = *(const float4*)(gp_ + (size_t)j_ * (8 * B_SZ * I_SZ) + 4); \
    } } while (0)

// convert prefetched fp32 regs -> bf16 -> ds_write into As (stride 72, 2-way banks)
#define CVTW(AR) do { \
    _Pragma("unroll") \
    for (int j_ = 0; j_ < 4; ++j_) { \
      union { __bf16 h[8]; uint4 v; } uvt_; \
      uvt_.h[0] = (__bf16)AR[2*j_].x;   uvt_.h[1] = (__bf16)AR[2*j_].y; \
      uvt_.h[2] = (__bf16)AR[2*j_].z;   uvt_.h[3] = (__bf16)AR[2*j_].w; \
      uvt_.h[4] = (__bf16)AR[2*j_+1].x; uvt_.h[5] = (__bf16)AR[2*j_+1].y; \
      uvt_.h[6] = (__bf16)AR[2*j_+1].z; uvt_.h[7] = (__bf16)AR[2*j_+1].w; \
      *(uint4*)&As[(arow0 + j_ * 8) * 72 + (lane & 7) * 8] = uvt_.v; \
    } } while (0)

#define SCAN16(colp, s0_) do { \
    ushort4 v0 = *(const ushort4*)&(colp)[(s0_)]; \
    ushort4 v1 = *(const ushort4*)&(colp)[(s0_) + 4]; \
    ushort4 v2 = *(const ushort4*)&(colp)[(s0_) + 8]; \
    ushort4 v3 = *(const ushort4*)&(colp)[(s0_) + 12]; \
    p = fmaf(c, fabsf(p), bf2f(v0.x)); p = fmaf(c, fabsf(p), bf2f(v0.y)); \
    p = fmaf(c, fabsf(p), bf2f(v0.z)); p = fmaf(c, fabsf(p), bf2f(v0.w)); \
    p = fmaf(c, fabsf(p), bf2f(v1.x)); p = fmaf(c, fabsf(p), bf2f(v1.y)); \
    p = fmaf(c, fabsf(p), bf2f(v1.z)); p = fmaf(c, fabsf(p), bf2f(v1.w)); \
    p = fmaf(c, fabsf(p), bf2f(v2.x)); p = fmaf(c, fabsf(p), bf2f(v2.y)); \
    p = fmaf(c, fabsf(p), bf2f(v2.z)); p = fmaf(c, fabsf(p), bf2f(v2.w)); \
    p = fmaf(c, fabsf(p), bf2f(v3.x)); p = fmaf(c, fabsf(p), bf2f(v3.y)); \
    p = fmaf(c, fabsf(p), bf2f(v3.z)); p = fmaf(c, fabsf(p), bf2f(v3.w)); \
  } while (0)

// One K-step t = st*8 + kt. CUR holds fp32 X for tile t+1 (consumed in staging),
// NXT receives the prefetch of tile t+2 (issued in the compute region so the
// __syncthreads drain comes after ~a full MFMA phase of cover).
// Order: [compute: prefetch(NXT,t+2), frag ds_reads + MFMA] -> sync ->
//        [staging: B gload_lds(t+1), cvt+ds_write A(t+1) from CUR,
//         scan chunk kt of s-tile (t>>3)-1] -> sync -> [kt==7: acc -> Cs].
// Epilogue is AFTER the 2nd sync so it cannot race the last scan chunk of the
// previous s-tile (which reads Cs in the staging region of this same t).
#define BODY(T, CUR, NXT) do { \
    const int t_ = (T); \
    const int kt_ = t_ & 7; \
    if (kt_ == 0) { \
      _Pragma("unroll") \
      for (int mi_ = 0; mi_ < 4; ++mi_) \
        _Pragma("unroll") \
        for (int ni_ = 0; ni_ < 4; ++ni_) { \
          f32x4 z_ = {0.f, 0.f, 0.f, 0.f}; \
          acc[mi_][ni_] = z_; \
        } \
    } \
    if (t_ < 62) { PREF(NXT, t_ + 2); } \
    _Pragma("unroll") \
    for (int ks_ = 0; ks_ < 2; ++ks_) { \
      bf16x8 af_[4], bf_[4]; \
      _Pragma("unroll") \
      for (int i_ = 0; i_ < 4; ++i_) { \
        af_[i_] = *(const bf16x8*)&As[arow[i_] + (ks_ * 4 + q) * 8]; \
        bf_[i_] = *(const bf16x8*)&Bs[brow[i_] + boff[ks_]]; \
      } \
      __builtin_amdgcn_s_setprio(1); \
      _Pragma("unroll") \
      for (int mi_ = 0; mi_ < 4; ++mi_) \
        _Pragma("unroll") \
        for (int ni_ = 0; ni_ < 4; ++ni_) \
          acc[mi_][ni_] = __builtin_amdgcn_mfma_f32_16x16x32_bf16( \
              af_[mi_], bf_[ni_], acc[mi_][ni_], 0, 0, 0); \
      __builtin_amdgcn_s_setprio(0); \
    } \
    __syncthreads();  /* frag reads of t done; NXT loads drained (covered) */ \
    if (t_ < 63) { \
      const int k1_ = (t_ + 1) & 7; \
      _Pragma("unroll") \
      for (int jj_ = 0; jj_ < 4; ++jj_) \
        GLOAD_LDS16(gB + (size_t)(jj_ * 8) * I_SZ + k1_ * 64, lB + jj_ * 512); \
      CVTW(CUR); \
    } \
    if (t_ >= 8 && tid < 128) { \
      const ushort* col_ = &Cs[tid * 132]; \
      SCAN16(col_, kt_ * 16); \
    } \
    __syncthreads();  /* tile t+1 visible */ \
    if (kt_ == 7) { \
      const int sb_ = wm + q * 4; \
      _Pragma("unroll") \
      for (int mi_ = 0; mi_ < 4; ++mi_) \
        _Pragma("unroll") \
        for (int ni_ = 0; ni_ < 4; ++ni_) { \
          ushort4 o_; \
          o_.x = f2bf(acc[mi_][ni_][0]); o_.y = f2bf(acc[mi_][ni_][1]); \
          o_.z = f2bf(acc[mi_][ni_][2]); o_.w = f2bf(acc[mi_][ni_][3]); \
          *(ushort4*)&Cs[(wn + ni_ * 16 + ml) * 132 + sb_ + mi_ * 16] = o_; \
        } \
    } \
  } while (0)

// ---------------------------------------------------------------- fused GEMM + scan + projection
// Grid: 1024 blocks = (b, ht). Round-0 schedule (plain __syncthreads, compiler-
// scheduled ds_read/MFMA interleave, no asm waits, no sched_barriers) with:
//  - A-prefetch moved into the compute region (ping-pong arA/arB) so the
//    barrier's vmcnt(0) drain comes after MFMA cover instead of immediately;
//  - Cs de-overlaid; serial scan chopped into 16-step chunks in the staging
//    shadow; epilogue moved post-barrier;
//  - final projection fused into the tail (Y pre-seeded with bias).
__global__ __launch_bounds__(256, 2) void fused_gemm_scan_kernel(
    const float* __restrict__ X,      // [1024][64][512] fp32
    const ushort* __restrict__ Wbf,   // [2048][512] bf16
    const float* __restrict__ hh,     // [2048]
    const float* __restrict__ Who,    // [512][2048] fp32
    float* __restrict__ Y) {          // [64][512], pre-seeded with bias
  __shared__ __align__(16) ushort smem[34304];   // 68608 B -> 2 blocks/CU
  ushort* As = smem;                  // [128][72]
  ushort* Bs = smem + 9216;           // [128][64], rotate-swizzled
  ushort* Cs = smem + 17408;          // [128 h][132 s]

  const int tid  = threadIdx.x;
  const int wave = tid >> 6;
  const int lane = tid & 63;

  const int bid = blockIdx.x;
  const int xcd = bid & 7;            // XCD (bid%8 heuristic)
  const int g   = bid >> 3;           // 0..127
  const int b   = (xcd << 3) | (g & 7);  // same-b -> same XCD (X L2 reuse)
  const int ht  = g >> 3;             // h-tile 0..15

  const int wm = (wave >> 1) * 64;    // s-offset within tile
  const int wn = (wave & 1) * 64;     // h-offset within tile
  const int ml = lane & 15;
  const int q  = lane >> 4;

  // A staging assignment (register prefetch path, fp32 X read directly)
  const int arow0 = wave * 32 + (lane >> 3);
  const size_t offA = (size_t)arow0 * (B_SZ * I_SZ) + (size_t)b * I_SZ
                    + (size_t)((lane & 7) * 8);

  // B staging: wave stages 32 rows; slot s holds chunk (s - row)&7
  const int r0     = wave * 32;
  const int srow   = lane >> 3;
  const int schunk = ((lane & 7) - srow) & 7;
  const ushort* gB = Wbf + (size_t)(ht * 128 + r0 + srow) * I_SZ + schunk * 8;
  ushort* lB = Bs + r0 * 64;

  // fragment offsets
  int boff[2];
  boff[0] = ((q + ml) & 7) * 8;       // rotate swizzle, stride 64
  boff[1] = ((4 + q + ml) & 7) * 8;
  int arow[4], brow[4];
  #pragma unroll
  for (int i = 0; i < 4; ++i) {
    arow[i] = (wm + i * 16 + ml) * 72;
    brow[i] = (wn + i * 16 + ml) * 64;
  }

  float c = 0.0f, p = 0.0f;           // scan state (p: pre-abs h)
  if (tid < 128) c = hh[ht * 128 + tid];

  float4 arA[8], arB[8];
  f32x4 acc[4][4];

  // ---------------- prologue: stage tile 0, prefetch arA <- tile 1
  PREF(arA, 0);
  #pragma unroll
  for (int jj = 0; jj < 4; ++jj)
    GLOAD_LDS16(gB + (size_t)(jj * 8) * I_SZ, lB + jj * 512);   // B tile0 (kt=0)
  CVTW(arA);                          // compiler inserts the vmcnt wait on arA
  PREF(arA, 1);                       // arA <- tile 1
  __syncthreads();                    // tile 0 visible (one exposed drain, ok)

  #pragma unroll 1
  for (int tt = 0; tt < 32; ++tt) {
    BODY(2 * tt,     arA, arB);
    BODY(2 * tt + 1, arB, arA);
  }

  __syncthreads();                    // Cs (st=7 epilogue) visible

  // ---- final s-tile scan + h handoff
  if (tid < 128) {
    const ushort* col = &Cs[tid * 132];
    #pragma unroll
    for (int s0 = 0; s0 < 128; s0 += 16) {
      SCAN16(col, s0);
    }
    ((float*)smem)[tid] = fabsf(p);   // h_s overlays As (free now)
  }
  __syncthreads();

  // ---- Y[b, :] += h . Who[:, ht*128 .. +128)   (Who slice is L2-resident)
  {
    const float* hs = (const float*)smem;
    const float* w0 = Who + (size_t)tid * H_SZ + (size_t)ht * 128;
    const float* w1 = w0 + (size_t)256 * H_SZ;
    float y0 = 0.f, y1 = 0.f;
    #pragma unroll 8
    for (int k = 0; k < 128; k += 4) {
      float4 hv = *(const float4*)&hs[k];    // broadcast (same addr all lanes)
      float4 u0 = *(const float4*)&w0[k];
      float4 u1 = *(const float4*)&w1[k];
      y0 += hv.x * u0.x + hv.y * u0.y + hv.z * u0.z + hv.w * u0.w;
      y1 += hv.x * u1.x + hv.y * u1.y + hv.z * u1.z + hv.w * u1.w;
    }
    atomicAdd(&Y[(size_t)b * O_SZ + tid], y0);
    atomicAdd(&Y[(size_t)b * O_SZ + 256 + tid], y1);
  }
}

// ---------------------------------------------------------------- launch
extern "C" void kernel_launch(void* const* d_in, const int* in_sizes, int n_in,
                              void* d_out, int out_size, void* d_ws, size_t ws_size,
                              hipStream_t stream) {
  (void)in_sizes; (void)n_in; (void)out_size; (void)ws_size;
  const float* X   = (const float*)d_in[0];   // [1024][64][512]
  const float* Wih = (const float*)d_in[1];   // [2048][512]
  const float* hh  = (const float*)d_in[2];   // [2048]
  const float* Who = (const float*)d_in[3];   // [512][2048]
  const float* bho = (const float*)d_in[4];   // [512]
  float* Y = (float*)d_out;                   // [64][512]

  ushort* Wbf = (ushort*)d_ws;                // 2 MiB

  // W convert (tiny)
  {
    int n4w = (int)((size_t)H_SZ * I_SZ / 4);          // 262144
    convert_f32_bf16_kernel<<<n4w / 256, 256, 0, stream>>>(
        (const float4*)Wih, (ushort4*)Wbf, n4w);
  }

  // Y <- bias (must complete before fused kernel's atomics; stream-ordered)
  init_y_kernel<<<(B_SZ * O_SZ) / 256, 256, 0, stream>>>(bho, Y);

  // fused GEMM + scan + projection
  fused_gemm_scan_kernel<<<1024, 256, 0, stream>>>(X, Wbf, hh, Who, Y);
}